// Round 7
// baseline (182.642 us; speedup 1.0000x reference)
//
#include <hip/hip_runtime.h>
#include <hip/hip_bf16.h>

typedef __hip_bfloat16 bf16;
typedef __attribute__((ext_vector_type(8))) short bf16x8;
typedef __attribute__((ext_vector_type(4))) float f32x4;

#define BATCH 4
#define CIN   512
#define HW    64
#define NPIX  4096
#define CALL  3072
#define NHEAD 128
#define EPS_LITE 1e-15f
#define BN_EPS   1e-5f

// Workspace (bytes), total ~138.2 MiB:
//   qkv_all (bf16): 0         .. 100663296
//   attT/xT (bf16): 100663296 .. 134217728   (xT aliases attT; dead before k_att3)
//   part    (f32) : 134217728 .. 135397376
//   (unused)      : 135397376 .. 135544832
//   Wbf     (bf16): 135544832 .. 137117696
//   Pbf     (bf16): 137117696 .. 138166272

__device__ __forceinline__ short f2bf(float f) {
    __hip_bfloat16 h = __float2bfloat16(f);
    short s; __builtin_memcpy(&s, &h, 2); return s;
}
__device__ __forceinline__ float bfl(unsigned u) {
    unsigned v = u << 16; float f; __builtin_memcpy(&f, &v, 4); return f;
}
__device__ __forceinline__ float bfh(unsigned u) {
    unsigned v = u & 0xffff0000u; float f; __builtin_memcpy(&f, &v, 4); return f;
}
__device__ __forceinline__ unsigned packbf(float a, float b) {
    return (unsigned)(unsigned short)f2bf(a) | ((unsigned)(unsigned short)f2bf(b) << 16);
}
__device__ __forceinline__ void gll16(const void* gsrc, void* ldst) {
    __builtin_amdgcn_global_load_lds(
        (const __attribute__((address_space(1))) unsigned int*)gsrc,
        (__attribute__((address_space(3))) unsigned int*)ldst, 16, 0, 0);
}

// ---------------------------------------------------------------------------
// Pre-pass A: weights -> bf16. (unchanged)
__global__ __launch_bounds__(256) void k_cvtw(const float* __restrict__ wq,
                                              const float* __restrict__ wk,
                                              const float* __restrict__ wv,
                                              const float* __restrict__ pj,
                                              bf16* __restrict__ Wbf,
                                              bf16* __restrict__ Pbf) {
    const int e = (blockIdx.x * 256 + threadIdx.x) * 4;
    const float* s; bf16* dst;
    if (e < 786432) {
        int o;
        if (e < 262144)      { s = wq; o = e; }
        else if (e < 524288) { s = wk; o = e - 262144; }
        else                 { s = wv; o = e - 524288; }
        f32x4 v = *(const f32x4*)(s + o);
        dst = Wbf + e;
        *(ushort2*)dst = make_ushort2((unsigned short)f2bf(v[0]), (unsigned short)f2bf(v[1]));
        *(ushort2*)(dst + 2) = make_ushort2((unsigned short)f2bf(v[2]), (unsigned short)f2bf(v[3]));
    } else {
        const int o = e - 786432;
        f32x4 v = *(const f32x4*)(pj + o);
        dst = Pbf + o;
        *(ushort2*)dst = make_ushort2((unsigned short)f2bf(v[0]), (unsigned short)f2bf(v[1]));
        *(ushort2*)(dst + 2) = make_ushort2((unsigned short)f2bf(v[2]), (unsigned short)f2bf(v[3]));
    }
}

// ---------------------------------------------------------------------------
// Pre-pass B: transpose+convert x -> xT [b][px][512] bf16. (unchanged)
__global__ __launch_bounds__(256) void k_cvtx(const float* __restrict__ x,
                                              bf16* __restrict__ xT) {
    __shared__ short lds[64][72];
    const int t   = threadIdx.x;
    const int px0 = blockIdx.x * 64;
    const int k0  = blockIdx.y * 64;
    const int b   = blockIdx.z;

    const int pr = t & 15, rr = t >> 4;
#pragma unroll
    for (int it = 0; it < 4; ++it) {
        const int row = it * 16 + rr;
        f32x4 v = *(const f32x4*)(x + (size_t)(b * CIN + k0 + row) * NPIX + px0 + pr * 4);
#pragma unroll
        for (int i = 0; i < 4; ++i) lds[pr * 4 + i][row] = f2bf(v[i]);
    }
    __syncthreads();

    const int px = t >> 2, kc = t & 3;
    uint4 u0 = *(const uint4*)&lds[px][kc * 16];
    uint4 u1 = *(const uint4*)&lds[px][kc * 16 + 8];
    bf16* dst = xT + ((size_t)b * NPIX + px0 + px) * 512 + k0 + kc * 16;
    *(uint4*)dst = u0;
    *(uint4*)(dst + 8) = u1;
}

// ---------------------------------------------------------------------------
// MFMA GEMM v3 (gll16 both operands). (unchanged)
template<int KD, int MT, bool PROJ>
__global__ __launch_bounds__(256) void k_gemm3(
        const bf16* __restrict__ Xt,
        const bf16* __restrict__ Wb,
        bf16* __restrict__ Obf,
        const float* __restrict__ gm, const float* __restrict__ bt,
        const float* __restrict__ mu, const float* __restrict__ va,
        const float* __restrict__ resid, float* __restrict__ Of)
{
    constexpr int NT = KD / 32;
    constexpr int MS = MT / 32;
    constexpr int AG = MT / 64;
    __shared__ short Ald[2][MT * 32];
    __shared__ short Bld[2][128 * 32];

    const int t    = threadIdx.x;
    const int lane = t & 63;
    const int w    = t >> 6;
    const int wm   = w >> 1, wn = w & 1;
    const int n0   = blockIdx.x * 128;
    const int c0   = blockIdx.y * MT;
    const int b    = blockIdx.z;

    const bf16* abase = Wb + (size_t)(c0 + w * (MT / 4) + (lane >> 2)) * KD + (lane & 3) * 8;
    const bf16* bbase = Xt + ((size_t)b * NPIX + n0 + w * 32 + (lane >> 2)) * KD + (lane & 3) * 8;

    auto stage = [&](int s, int buf) {
#pragma unroll
        for (int q = 0; q < AG; ++q)
            gll16(abase + (size_t)q * 16 * KD + s * 32,
                  &Ald[buf][(w * (MT / 4) + q * 16) * 32]);
#pragma unroll
        for (int q = 0; q < 2; ++q)
            gll16(bbase + (size_t)q * 16 * KD + s * 32,
                  &Bld[buf][(w * 32 + q * 16) * 32]);
    };

    f32x4 acc[MS][4];
#pragma unroll
    for (int ms = 0; ms < MS; ++ms)
#pragma unroll
        for (int ns = 0; ns < 4; ++ns)
#pragma unroll
            for (int j = 0; j < 4; ++j) acc[ms][ns][j] = 0.f;

    stage(0, 0);
    __syncthreads();

    const int l15 = lane & 15, l4 = lane >> 4;
    for (int s = 0; s < NT; ++s) {
        const int cur = s & 1;
        if (s + 1 < NT) stage(s + 1, cur ^ 1);

        bf16x8 af[MS], bv[4];
#pragma unroll
        for (int ms = 0; ms < MS; ++ms)
            af[ms] = *(const bf16x8*)&Ald[cur][(wm * (MT / 2) + ms * 16 + l15) * 32 + l4 * 8];
#pragma unroll
        for (int ns = 0; ns < 4; ++ns)
            bv[ns] = *(const bf16x8*)&Bld[cur][(wn * 64 + ns * 16 + l15) * 32 + l4 * 8];
#pragma unroll
        for (int ms = 0; ms < MS; ++ms)
#pragma unroll
            for (int ns = 0; ns < 4; ++ns)
                acc[ms][ns] = __builtin_amdgcn_mfma_f32_16x16x32_bf16(
                    af[ms], bv[ns], acc[ms][ns], 0, 0, 0);

        __syncthreads();
    }

    if (!PROJ) {
#pragma unroll
        for (int ms = 0; ms < MS; ++ms) {
            const int crow = c0 + wm * (MT / 2) + ms * 16 + l4 * 4;
#pragma unroll
            for (int ns = 0; ns < 4; ++ns) {
                const int ncol = n0 + wn * 64 + ns * 16 + l15;
#pragma unroll
                for (int j = 0; j < 4; ++j) {
                    bf16 h; short sv = f2bf(acc[ms][ns][j]);
                    __builtin_memcpy(&h, &sv, 2);
                    Obf[((size_t)b * CALL + crow + j) * NPIX + ncol] = h;
                }
            }
        }
    } else {
#pragma unroll
        for (int ms = 0; ms < MS; ++ms) {
            const int crow = c0 + wm * (MT / 2) + ms * 16 + l4 * 4;
#pragma unroll
            for (int j = 0; j < 4; ++j) {
                const int o = crow + j;
                const float inv = gm[o] / sqrtf(va[o] + BN_EPS);
                const float sh  = bt[o] - mu[o] * inv;
#pragma unroll
                for (int ns = 0; ns < 4; ++ns) {
                    const int ncol = n0 + wn * 64 + ns * 16 + l15;
                    const size_t idx = ((size_t)b * 512 + o) * NPIX + ncol;
                    Of[idx] = acc[ms][ns][j] * inv + sh + resid[idx];
                }
            }
        }
    }
}

// ---------------------------------------------------------------------------
// K2 v3: depthwise 5x5 + grouped 1x1. 512 threads, 32-row stripe.
// grid (2, 192, 4). LDS: in 8ch x 36rows x 80cols + dw 8ch x 32x64. ~79 KB
// -> 2 blocks/CU (16 waves, ~50% occupancy).
#define DW_ICS (36 * 80)    // in_lds ch stride (shorts), 16B-aligned
#define DW_DCS (32 * 64)    // dw_lds ch stride (shorts), 16B-aligned
__global__ __launch_bounds__(512) void k_dwpw(const float* __restrict__ dwk,
                                              const float* __restrict__ pwk,
                                              bf16* __restrict__ qkv_all) {
    __shared__ short in_lds[8 * DW_ICS];   // [ch][36 rows][80 cols], px = col-8
    __shared__ short dw_lds[8 * DW_DCS];   // [ch][32 rows][64 px]

    const int t  = threadIdx.x;
    const int g  = blockIdx.y;
    const int b  = blockIdx.z;
    const int y0 = blockIdx.x * 32;

    // ---- phase 0: stage rows y0-2 .. y0+33, zero-padded; uint4 segs ----
    const bf16* src = qkv_all + ((size_t)b * CALL + g * 8) * NPIX;
#pragma unroll
    for (int i = 0; i < 6; ++i) {
        const int v = i * 512 + t;
        if (v < 2880) {                      // 8ch * 36rows * 10segs
            const int ch  = v / 360;
            const int rem = v % 360;
            const int row = rem / 10;
            const int seg = rem % 10;
            const int grow = y0 + row - 2;
            uint4 val = make_uint4(0u, 0u, 0u, 0u);
            if (seg >= 1 && seg <= 8 && grow >= 0 && grow < HW)
                val = *(const uint4*)(src + (size_t)ch * NPIX + grow * HW + (seg - 1) * 8);
            *(uint4*)&in_lds[ch * DW_ICS + row * 80 + seg * 8] = val;
        }
    }

    const int lane = t & 63;
    const int w    = t >> 6;                 // 8 waves, rows w*4..w*4+3
    const int xb   = lane & 7;
    const int ch   = lane >> 3;
    const int x0   = xb * 8;

    float kc[25];
    {
        const float* kp = dwk + (size_t)(g * 8 + ch) * 25;
#pragma unroll
        for (int i = 0; i < 25; ++i) kc[i] = kp[i];
    }
    __syncthreads();

    // ---- phase 1: depthwise, sliding 5-row register window ----
    float A[5][12];
    const short* cb = &in_lds[ch * DW_ICS + x0];

    auto loadrow = [&](int L, float* f) {
        const short* rp = cb + L * 80;
        uint2 lo = *(const uint2*)(rp + 4);
        uint4 md = *(const uint4*)(rp + 8);
        uint2 hi = *(const uint2*)(rp + 16);
        f[0]  = bfl(lo.y); f[1]  = bfh(lo.y);
        f[2]  = bfl(md.x); f[3]  = bfh(md.x);
        f[4]  = bfl(md.y); f[5]  = bfh(md.y);
        f[6]  = bfl(md.z); f[7]  = bfh(md.z);
        f[8]  = bfl(md.w); f[9]  = bfh(md.w);
        f[10] = bfl(hi.x); f[11] = bfh(hi.x);
    };

    const int r0 = w * 4;
    loadrow(r0 + 0, A[0]);
    loadrow(r0 + 1, A[1]);
    loadrow(r0 + 2, A[2]);
    loadrow(r0 + 3, A[3]);

#pragma unroll
    for (int ri = 0; ri < 4; ++ri) {
        loadrow(r0 + ri + 4, A[(ri + 4) % 5]);
        float acc[8];
#pragma unroll
        for (int i = 0; i < 8; ++i) acc[i] = 0.f;
#pragma unroll
        for (int dy = 0; dy < 5; ++dy) {
            const float* Ar = A[(ri + dy) % 5];
#pragma unroll
            for (int dx = 0; dx < 5; ++dx) {
                const float kv = kc[dy * 5 + dx];
#pragma unroll
                for (int i = 0; i < 8; ++i)
                    acc[i] += Ar[i + dx] * kv;
            }
        }
        uint4 pk;
        pk.x = packbf(acc[0], acc[1]);
        pk.y = packbf(acc[2], acc[3]);
        pk.z = packbf(acc[4], acc[5]);
        pk.w = packbf(acc[6], acc[7]);
        *(uint4*)&dw_lds[ch * DW_DCS + (r0 + ri) * 64 + x0] = pk;
    }
    __syncthreads();

    // ---- phase 2: pointwise 8->8; pwk block-uniform -> s_loads ----
    const float* pwb = pwk + (size_t)g * 64;
#pragma unroll
    for (int it = 0; it < 2; ++it) {
        const int p2 = (it * 512 + t) * 2;   // even pixel index in 2048-px stripe
        float v0[8], v1[8];
#pragma unroll
        for (int ci = 0; ci < 8; ++ci) {
            const unsigned u = *(const unsigned*)&dw_lds[ci * DW_DCS + p2];
            v0[ci] = bfl(u); v1[ci] = bfh(u);
        }
        bf16* op = qkv_all + ((size_t)b * CALL + 1536 + g * 8) * NPIX + y0 * HW + p2;
#pragma unroll
        for (int o = 0; o < 8; ++o) {
            float s0 = 0.f, s1 = 0.f;
#pragma unroll
            for (int ci = 0; ci < 8; ++ci) {
                const float wv = pwb[o * 8 + ci];
                s0 += wv * v0[ci]; s1 += wv * v1[ci];
            }
            *(unsigned*)(op + (size_t)o * NPIX) = packbf(s0, s1);
        }
    }
}

// ---------------------------------------------------------------------------
// K3: scores partials. (unchanged)
__global__ __launch_bounds__(64) void k_scores(const bf16* __restrict__ qkv_all,
                                               float* __restrict__ part) {
    const int lane = threadIdx.x;
    const int h = blockIdx.y;
    const int b = blockIdx.z;
    const bf16* base = qkv_all + ((size_t)b * CALL + h * 24) * NPIX;

    float acc[72];
#pragma unroll
    for (int i = 0; i < 72; ++i) acc[i] = 0.f;

    for (int it = 0; it < 4; ++it) {
        const int n = blockIdx.x * 512 + it * 128 + lane * 2;
        const bf16* p = base + n;
        float k0[8], k1[8], v0[8], v1[8];
#pragma unroll
        for (int e = 0; e < 8; ++e) {
            const unsigned u = *(const unsigned*)&p[(size_t)(8 + e) * NPIX];
            k0[e] = fmaxf(bfl(u), 0.f); k1[e] = fmaxf(bfh(u), 0.f);
        }
#pragma unroll
        for (int d = 0; d < 8; ++d) {
            const unsigned u = *(const unsigned*)&p[(size_t)(16 + d) * NPIX];
            v0[d] = bfl(u); v1[d] = bfh(u);
        }
#pragma unroll
        for (int d = 0; d < 9; ++d) {
            const float vd0 = (d < 8) ? v0[d] : 1.f;
            const float vd1 = (d < 8) ? v1[d] : 1.f;
#pragma unroll
            for (int e = 0; e < 8; ++e)
                acc[d * 8 + e] += vd0 * k0[e] + vd1 * k1[e];
        }
    }

    const int bh = b * NHEAD + h;
#pragma unroll
    for (int i = 0; i < 72; ++i) {
        float v = acc[i];
        for (int off = 32; off; off >>= 1) v += __shfl_xor(v, off, 64);
        if (lane == 0) part[((size_t)bh * 72 + i) * 8 + blockIdx.x] = v;
    }
}

// ---------------------------------------------------------------------------
// K4: att with fused partial-reduction (scores2) + TRANSPOSED output
// attT[b][px][1024]. grid (16, 128, 4), block 256.
__global__ __launch_bounds__(256) void k_att3(const bf16* __restrict__ qkv_all,
                                              const float* __restrict__ part,
                                              bf16* __restrict__ attT) {
    __shared__ float sc[72];
    const int t  = threadIdx.x;
    const int h  = blockIdx.y;
    const int b  = blockIdx.z;
    const int bh = b * NHEAD + h;

    if (t < 72) {
        float s = 0.f;
#pragma unroll
        for (int ns = 0; ns < 8; ++ns) s += part[((size_t)bh * 72 + t) * 8 + ns];
        sc[t] = s;
    }
    __syncthreads();

    const int px = blockIdx.x * 256 + t;
    const bf16* qb = qkv_all + ((size_t)b * CALL + h * 24) * NPIX + px;
    float q[8];
#pragma unroll
    for (int e = 0; e < 8; ++e)
        q[e] = fmaxf(__bfloat162float(qb[(size_t)e * NPIX]), 0.f);

    float num[9];
#pragma unroll
    for (int d = 0; d < 9; ++d) {
        float s = 0.f;
#pragma unroll
        for (int e = 0; e < 8; ++e) s += sc[d * 8 + e] * q[e];   // LDS broadcast
        num[d] = s;
    }
    const float inv = 1.f / (num[8] + EPS_LITE);
    uint4 pk;
    pk.x = packbf(num[0] * inv, num[1] * inv);
    pk.y = packbf(num[2] * inv, num[3] * inv);
    pk.z = packbf(num[4] * inv, num[5] * inv);
    pk.w = packbf(num[6] * inv, num[7] * inv);
    *(uint4*)(attT + ((size_t)b * NPIX + px) * 1024 + h * 8) = pk;
}

// ---------------------------------------------------------------------------
extern "C" void kernel_launch(void* const* d_in, const int* in_sizes, int n_in,
                              void* d_out, int out_size, void* d_ws, size_t ws_size,
                              hipStream_t stream) {
    const float* x   = (const float*)d_in[0];
    const float* wq  = (const float*)d_in[1];
    const float* wk  = (const float*)d_in[2];
    const float* wv  = (const float*)d_in[3];
    const float* dwk = (const float*)d_in[4];
    const float* pwk = (const float*)d_in[5];
    const float* pj  = (const float*)d_in[6];
    const float* gm  = (const float*)d_in[7];
    const float* bt  = (const float*)d_in[8];
    const float* mu  = (const float*)d_in[9];
    const float* va  = (const float*)d_in[10];
    float* out = (float*)d_out;

    char* ws = (char*)d_ws;
    bf16*  qkv_all = (bf16*)(ws);
    bf16*  attT    = (bf16*)(ws + 100663296);
    bf16*  xT      = (bf16*)(ws + 100663296);   // aliases attT; dead before k_att3
    float* part    = (float*)(ws + 134217728);
    bf16*  Wbf     = (bf16*)(ws + 135544832);
    bf16*  Pbf     = (bf16*)(ws + 137117696);

    k_cvtw<<<dim3(1280), 256, 0, stream>>>(wq, wk, wv, pj, Wbf, Pbf);
    k_cvtx<<<dim3(64, 8, BATCH), 256, 0, stream>>>(x, xT);
    // QKV: M=1536, K=512
    k_gemm3<512, 128, false><<<dim3(32, 12, BATCH), 256, 0, stream>>>(
        xT, Wbf, qkv_all, nullptr, nullptr, nullptr, nullptr, nullptr, nullptr);
    k_dwpw  <<<dim3( 2, 192, BATCH), 512, 0, stream>>>(dwk, pwk, qkv_all);
    k_scores<<<dim3( 8, 128, BATCH),  64, 0, stream>>>(qkv_all, part);
    k_att3  <<<dim3(16, 128, BATCH), 256, 0, stream>>>(qkv_all, part, attT);
    // Proj: M=512, K=1024, + BN + residual
    k_gemm3<1024, 64, true><<<dim3(32, 8, BATCH), 256, 0, stream>>>(
        attT, Pbf, nullptr, gm, bt, mu, va, x, out);
}

// Round 8
// 172.850 us; speedup vs baseline: 1.0566x; 1.0566x over previous
//
#include <hip/hip_runtime.h>
#include <hip/hip_bf16.h>

typedef __hip_bfloat16 bf16;
typedef __attribute__((ext_vector_type(8))) short bf16x8;
typedef __attribute__((ext_vector_type(4))) float f32x4;

#define BATCH 4
#define CIN   512
#define HW    64
#define NPIX  4096
#define CALL  3072
#define NHEAD 128
#define EPS_LITE 1e-15f
#define BN_EPS   1e-5f

// Workspace (bytes), total ~138.2 MiB:
//   qkv_all (bf16): 0         .. 100663296
//   attT/xT (bf16): 100663296 .. 134217728   (xT aliases attT; dead before k_att3)
//   part    (f32) : 134217728 .. 135397376
//   Wbf     (bf16): 135544832 .. 137117696
//   Pbf     (bf16): 137117696 .. 138166272

__device__ __forceinline__ short f2bf(float f) {
    __hip_bfloat16 h = __float2bfloat16(f);
    short s; __builtin_memcpy(&s, &h, 2); return s;
}
__device__ __forceinline__ float bfl(unsigned u) {
    unsigned v = u << 16; float f; __builtin_memcpy(&f, &v, 4); return f;
}
__device__ __forceinline__ float bfh(unsigned u) {
    unsigned v = u & 0xffff0000u; float f; __builtin_memcpy(&f, &v, 4); return f;
}
__device__ __forceinline__ unsigned packbf(float a, float b) {
    return (unsigned)(unsigned short)f2bf(a) | ((unsigned)(unsigned short)f2bf(b) << 16);
}
__device__ __forceinline__ void gll16(const void* gsrc, void* ldst) {
    __builtin_amdgcn_global_load_lds(
        (const __attribute__((address_space(1))) unsigned int*)gsrc,
        (__attribute__((address_space(3))) unsigned int*)ldst, 16, 0, 0);
}

// ---------------------------------------------------------------------------
// Pre-pass A: weights -> bf16. (unchanged)
__global__ __launch_bounds__(256) void k_cvtw(const float* __restrict__ wq,
                                              const float* __restrict__ wk,
                                              const float* __restrict__ wv,
                                              const float* __restrict__ pj,
                                              bf16* __restrict__ Wbf,
                                              bf16* __restrict__ Pbf) {
    const int e = (blockIdx.x * 256 + threadIdx.x) * 4;
    const float* s; bf16* dst;
    if (e < 786432) {
        int o;
        if (e < 262144)      { s = wq; o = e; }
        else if (e < 524288) { s = wk; o = e - 262144; }
        else                 { s = wv; o = e - 524288; }
        f32x4 v = *(const f32x4*)(s + o);
        dst = Wbf + e;
        *(ushort2*)dst = make_ushort2((unsigned short)f2bf(v[0]), (unsigned short)f2bf(v[1]));
        *(ushort2*)(dst + 2) = make_ushort2((unsigned short)f2bf(v[2]), (unsigned short)f2bf(v[3]));
    } else {
        const int o = e - 786432;
        f32x4 v = *(const f32x4*)(pj + o);
        dst = Pbf + o;
        *(ushort2*)dst = make_ushort2((unsigned short)f2bf(v[0]), (unsigned short)f2bf(v[1]));
        *(ushort2*)(dst + 2) = make_ushort2((unsigned short)f2bf(v[2]), (unsigned short)f2bf(v[3]));
    }
}

// ---------------------------------------------------------------------------
// Pre-pass B: transpose+convert x -> xT [b][px][512] bf16. (unchanged)
__global__ __launch_bounds__(256) void k_cvtx(const float* __restrict__ x,
                                              bf16* __restrict__ xT) {
    __shared__ short lds[64][72];
    const int t   = threadIdx.x;
    const int px0 = blockIdx.x * 64;
    const int k0  = blockIdx.y * 64;
    const int b   = blockIdx.z;

    const int pr = t & 15, rr = t >> 4;
#pragma unroll
    for (int it = 0; it < 4; ++it) {
        const int row = it * 16 + rr;
        f32x4 v = *(const f32x4*)(x + (size_t)(b * CIN + k0 + row) * NPIX + px0 + pr * 4);
#pragma unroll
        for (int i = 0; i < 4; ++i) lds[pr * 4 + i][row] = f2bf(v[i]);
    }
    __syncthreads();

    const int px = t >> 2, kc = t & 3;
    uint4 u0 = *(const uint4*)&lds[px][kc * 16];
    uint4 u1 = *(const uint4*)&lds[px][kc * 16 + 8];
    bf16* dst = xT + ((size_t)b * NPIX + px0 + px) * 512 + k0 + kc * 16;
    *(uint4*)dst = u0;
    *(uint4*)(dst + 8) = u1;
}

// ---------------------------------------------------------------------------
// MFMA GEMM v3 (gll16 both operands). (unchanged)
template<int KD, int MT, bool PROJ>
__global__ __launch_bounds__(256) void k_gemm3(
        const bf16* __restrict__ Xt,
        const bf16* __restrict__ Wb,
        bf16* __restrict__ Obf,
        const float* __restrict__ gm, const float* __restrict__ bt,
        const float* __restrict__ mu, const float* __restrict__ va,
        const float* __restrict__ resid, float* __restrict__ Of)
{
    constexpr int NT = KD / 32;
    constexpr int MS = MT / 32;
    constexpr int AG = MT / 64;
    __shared__ short Ald[2][MT * 32];
    __shared__ short Bld[2][128 * 32];

    const int t    = threadIdx.x;
    const int lane = t & 63;
    const int w    = t >> 6;
    const int wm   = w >> 1, wn = w & 1;
    const int n0   = blockIdx.x * 128;
    const int c0   = blockIdx.y * MT;
    const int b    = blockIdx.z;

    const bf16* abase = Wb + (size_t)(c0 + w * (MT / 4) + (lane >> 2)) * KD + (lane & 3) * 8;
    const bf16* bbase = Xt + ((size_t)b * NPIX + n0 + w * 32 + (lane >> 2)) * KD + (lane & 3) * 8;

    auto stage = [&](int s, int buf) {
#pragma unroll
        for (int q = 0; q < AG; ++q)
            gll16(abase + (size_t)q * 16 * KD + s * 32,
                  &Ald[buf][(w * (MT / 4) + q * 16) * 32]);
#pragma unroll
        for (int q = 0; q < 2; ++q)
            gll16(bbase + (size_t)q * 16 * KD + s * 32,
                  &Bld[buf][(w * 32 + q * 16) * 32]);
    };

    f32x4 acc[MS][4];
#pragma unroll
    for (int ms = 0; ms < MS; ++ms)
#pragma unroll
        for (int ns = 0; ns < 4; ++ns)
#pragma unroll
            for (int j = 0; j < 4; ++j) acc[ms][ns][j] = 0.f;

    stage(0, 0);
    __syncthreads();

    const int l15 = lane & 15, l4 = lane >> 4;
    for (int s = 0; s < NT; ++s) {
        const int cur = s & 1;
        if (s + 1 < NT) stage(s + 1, cur ^ 1);

        bf16x8 af[MS], bv[4];
#pragma unroll
        for (int ms = 0; ms < MS; ++ms)
            af[ms] = *(const bf16x8*)&Ald[cur][(wm * (MT / 2) + ms * 16 + l15) * 32 + l4 * 8];
#pragma unroll
        for (int ns = 0; ns < 4; ++ns)
            bv[ns] = *(const bf16x8*)&Bld[cur][(wn * 64 + ns * 16 + l15) * 32 + l4 * 8];
#pragma unroll
        for (int ms = 0; ms < MS; ++ms)
#pragma unroll
            for (int ns = 0; ns < 4; ++ns)
                acc[ms][ns] = __builtin_amdgcn_mfma_f32_16x16x32_bf16(
                    af[ms], bv[ns], acc[ms][ns], 0, 0, 0);

        __syncthreads();
    }

    if (!PROJ) {
#pragma unroll
        for (int ms = 0; ms < MS; ++ms) {
            const int crow = c0 + wm * (MT / 2) + ms * 16 + l4 * 4;
#pragma unroll
            for (int ns = 0; ns < 4; ++ns) {
                const int ncol = n0 + wn * 64 + ns * 16 + l15;
#pragma unroll
                for (int j = 0; j < 4; ++j) {
                    bf16 h; short sv = f2bf(acc[ms][ns][j]);
                    __builtin_memcpy(&h, &sv, 2);
                    Obf[((size_t)b * CALL + crow + j) * NPIX + ncol] = h;
                }
            }
        }
    } else {
#pragma unroll
        for (int ms = 0; ms < MS; ++ms) {
            const int crow = c0 + wm * (MT / 2) + ms * 16 + l4 * 4;
#pragma unroll
            for (int j = 0; j < 4; ++j) {
                const int o = crow + j;
                const float inv = gm[o] / sqrtf(va[o] + BN_EPS);
                const float sh  = bt[o] - mu[o] * inv;
#pragma unroll
                for (int ns = 0; ns < 4; ++ns) {
                    const int ncol = n0 + wn * 64 + ns * 16 + l15;
                    const size_t idx = ((size_t)b * 512 + o) * NPIX + ncol;
                    Of[idx] = acc[ms][ns][j] * inv + sh + resid[idx];
                }
            }
        }
    }
}

// ---------------------------------------------------------------------------
// K2 v5: depthwise 5x5 + grouped 1x1, SINGLE reused LDS buffer (25.7 KB).
// 256 threads, 16-row stripe, grid (4, 192, 4).
// phase0 stage -> phase1 dw into packed VGPRs -> barrier -> store dw back
// into the SAME LDS -> phase2 pointwise.
#define DW_ICS 1608   // input ch stride (shorts): 3216B, 16B-aligned, ch ≡ +4 banks
#define DW_DCS 1032   // dw    ch stride (shorts): 2064B, 16B-aligned, ch ≡ +4 banks
__global__ __launch_bounds__(256) void k_dwpw(const float* __restrict__ dwk,
                                              const float* __restrict__ pwk,
                                              bf16* __restrict__ qkv_all) {
    __shared__ short slds[8 * DW_ICS];   // 25728 B; reused for dw after barrier

    const int t  = threadIdx.x;
    const int g  = blockIdx.y;
    const int b  = blockIdx.z;
    const int y0 = blockIdx.x * 16;

    // ---- phase 0: stage rows y0-2 .. y0+17 (20 rows), zero-padded ----
    const bf16* src = qkv_all + ((size_t)b * CALL + g * 8) * NPIX;
#pragma unroll
    for (int i = 0; i < 7; ++i) {
        const int v = i * 256 + t;
        if (v < 1600) {                      // 8ch * 20rows * 10segs
            const int ch  = v / 200;
            const int rem = v % 200;
            const int row = rem / 10;
            const int seg = rem % 10;
            const int grow = y0 + row - 2;
            uint4 val = make_uint4(0u, 0u, 0u, 0u);
            if (seg >= 1 && seg <= 8 && grow >= 0 && grow < HW)
                val = *(const uint4*)(src + (size_t)ch * NPIX + grow * HW + (seg - 1) * 8);
            *(uint4*)&slds[ch * DW_ICS + row * 80 + seg * 8] = val;
        }
    }

    const int lane = t & 63;
    const int w    = t >> 6;                 // 4 waves -> dw rows w*4..w*4+3
    const int xb   = lane & 7;
    const int ch   = lane >> 3;
    const int x0   = xb * 8;

    float kc[25];
    {
        const float* kp = dwk + (size_t)(g * 8 + ch) * 25;
#pragma unroll
        for (int i = 0; i < 25; ++i) kc[i] = kp[i];
    }
    __syncthreads();

    // ---- phase 1: depthwise, sliding 5-row register window; results in regs ----
    float A[5][12];
    const short* cb = &slds[ch * DW_ICS + x0];

    auto loadrow = [&](int L, float* f) {
        const short* rp = cb + L * 80;
        uint2 lo = *(const uint2*)(rp + 4);
        uint4 md = *(const uint4*)(rp + 8);
        uint2 hi = *(const uint2*)(rp + 16);
        f[0]  = bfl(lo.y); f[1]  = bfh(lo.y);
        f[2]  = bfl(md.x); f[3]  = bfh(md.x);
        f[4]  = bfl(md.y); f[5]  = bfh(md.y);
        f[6]  = bfl(md.z); f[7]  = bfh(md.z);
        f[8]  = bfl(md.w); f[9]  = bfh(md.w);
        f[10] = bfl(hi.x); f[11] = bfh(hi.x);
    };

    const int r0 = w * 4;
    loadrow(r0 + 0, A[0]);
    loadrow(r0 + 1, A[1]);
    loadrow(r0 + 2, A[2]);
    loadrow(r0 + 3, A[3]);

    uint4 pk[4];
#pragma unroll
    for (int ri = 0; ri < 4; ++ri) {
        loadrow(r0 + ri + 4, A[(ri + 4) % 5]);
        float acc[8];
#pragma unroll
        for (int i = 0; i < 8; ++i) acc[i] = 0.f;
#pragma unroll
        for (int dy = 0; dy < 5; ++dy) {
            const float* Ar = A[(ri + dy) % 5];
#pragma unroll
            for (int dx = 0; dx < 5; ++dx) {
                const float kv = kc[dy * 5 + dx];
#pragma unroll
                for (int i = 0; i < 8; ++i)
                    acc[i] += Ar[i + dx] * kv;
            }
        }
        pk[ri].x = packbf(acc[0], acc[1]);
        pk[ri].y = packbf(acc[2], acc[3]);
        pk[ri].z = packbf(acc[4], acc[5]);
        pk[ri].w = packbf(acc[6], acc[7]);
    }
    __syncthreads();                          // all input reads done

    // ---- phase 1b: store dw into the same LDS ([ch][16 rows][64 px]) ----
#pragma unroll
    for (int ri = 0; ri < 4; ++ri)
        *(uint4*)&slds[ch * DW_DCS + (r0 + ri) * 64 + x0] = pk[ri];
    __syncthreads();

    // ---- phase 2: pointwise 8->8; pwk block-uniform -> s_loads ----
    const float* pwb = pwk + (size_t)g * 64;
#pragma unroll
    for (int it = 0; it < 2; ++it) {
        const int p2 = (it * 256 + t) * 2;    // even pixel index in 1024-px stripe
        float v0[8], v1[8];
#pragma unroll
        for (int ci = 0; ci < 8; ++ci) {
            const unsigned u = *(const unsigned*)&slds[ci * DW_DCS + p2];
            v0[ci] = bfl(u); v1[ci] = bfh(u);
        }
        bf16* op = qkv_all + ((size_t)b * CALL + 1536 + g * 8) * NPIX + y0 * HW + p2;
#pragma unroll
        for (int o = 0; o < 8; ++o) {
            float s0 = 0.f, s1 = 0.f;
#pragma unroll
            for (int ci = 0; ci < 8; ++ci) {
                const float wv = pwb[o * 8 + ci];
                s0 += wv * v0[ci]; s1 += wv * v1[ci];
            }
            *(unsigned*)(op + (size_t)o * NPIX) = packbf(s0, s1);
        }
    }
}

// ---------------------------------------------------------------------------
// K3: scores partials. (unchanged)
__global__ __launch_bounds__(64) void k_scores(const bf16* __restrict__ qkv_all,
                                               float* __restrict__ part) {
    const int lane = threadIdx.x;
    const int h = blockIdx.y;
    const int b = blockIdx.z;
    const bf16* base = qkv_all + ((size_t)b * CALL + h * 24) * NPIX;

    float acc[72];
#pragma unroll
    for (int i = 0; i < 72; ++i) acc[i] = 0.f;

    for (int it = 0; it < 4; ++it) {
        const int n = blockIdx.x * 512 + it * 128 + lane * 2;
        const bf16* p = base + n;
        float k0[8], k1[8], v0[8], v1[8];
#pragma unroll
        for (int e = 0; e < 8; ++e) {
            const unsigned u = *(const unsigned*)&p[(size_t)(8 + e) * NPIX];
            k0[e] = fmaxf(bfl(u), 0.f); k1[e] = fmaxf(bfh(u), 0.f);
        }
#pragma unroll
        for (int d = 0; d < 8; ++d) {
            const unsigned u = *(const unsigned*)&p[(size_t)(16 + d) * NPIX];
            v0[d] = bfl(u); v1[d] = bfh(u);
        }
#pragma unroll
        for (int d = 0; d < 9; ++d) {
            const float vd0 = (d < 8) ? v0[d] : 1.f;
            const float vd1 = (d < 8) ? v1[d] : 1.f;
#pragma unroll
            for (int e = 0; e < 8; ++e)
                acc[d * 8 + e] += vd0 * k0[e] + vd1 * k1[e];
        }
    }

    const int bh = b * NHEAD + h;
#pragma unroll
    for (int i = 0; i < 72; ++i) {
        float v = acc[i];
        for (int off = 32; off; off >>= 1) v += __shfl_xor(v, off, 64);
        if (lane == 0) part[((size_t)bh * 72 + i) * 8 + blockIdx.x] = v;
    }
}

// ---------------------------------------------------------------------------
// K4: att with fused partial-reduction + TRANSPOSED output. (unchanged)
__global__ __launch_bounds__(256) void k_att3(const bf16* __restrict__ qkv_all,
                                              const float* __restrict__ part,
                                              bf16* __restrict__ attT) {
    __shared__ float sc[72];
    const int t  = threadIdx.x;
    const int h  = blockIdx.y;
    const int b  = blockIdx.z;
    const int bh = b * NHEAD + h;

    if (t < 72) {
        float s = 0.f;
#pragma unroll
        for (int ns = 0; ns < 8; ++ns) s += part[((size_t)bh * 72 + t) * 8 + ns];
        sc[t] = s;
    }
    __syncthreads();

    const int px = blockIdx.x * 256 + t;
    const bf16* qb = qkv_all + ((size_t)b * CALL + h * 24) * NPIX + px;
    float q[8];
#pragma unroll
    for (int e = 0; e < 8; ++e)
        q[e] = fmaxf(__bfloat162float(qb[(size_t)e * NPIX]), 0.f);

    float num[9];
#pragma unroll
    for (int d = 0; d < 9; ++d) {
        float s = 0.f;
#pragma unroll
        for (int e = 0; e < 8; ++e) s += sc[d * 8 + e] * q[e];
        num[d] = s;
    }
    const float inv = 1.f / (num[8] + EPS_LITE);
    uint4 pk;
    pk.x = packbf(num[0] * inv, num[1] * inv);
    pk.y = packbf(num[2] * inv, num[3] * inv);
    pk.z = packbf(num[4] * inv, num[5] * inv);
    pk.w = packbf(num[6] * inv, num[7] * inv);
    *(uint4*)(attT + ((size_t)b * NPIX + px) * 1024 + h * 8) = pk;
}

// ---------------------------------------------------------------------------
extern "C" void kernel_launch(void* const* d_in, const int* in_sizes, int n_in,
                              void* d_out, int out_size, void* d_ws, size_t ws_size,
                              hipStream_t stream) {
    const float* x   = (const float*)d_in[0];
    const float* wq  = (const float*)d_in[1];
    const float* wk  = (const float*)d_in[2];
    const float* wv  = (const float*)d_in[3];
    const float* dwk = (const float*)d_in[4];
    const float* pwk = (const float*)d_in[5];
    const float* pj  = (const float*)d_in[6];
    const float* gm  = (const float*)d_in[7];
    const float* bt  = (const float*)d_in[8];
    const float* mu  = (const float*)d_in[9];
    const float* va  = (const float*)d_in[10];
    float* out = (float*)d_out;

    char* ws = (char*)d_ws;
    bf16*  qkv_all = (bf16*)(ws);
    bf16*  attT    = (bf16*)(ws + 100663296);
    bf16*  xT      = (bf16*)(ws + 100663296);   // aliases attT; dead before k_att3
    float* part    = (float*)(ws + 134217728);
    bf16*  Wbf     = (bf16*)(ws + 135544832);
    bf16*  Pbf     = (bf16*)(ws + 137117696);

    k_cvtw<<<dim3(1280), 256, 0, stream>>>(wq, wk, wv, pj, Wbf, Pbf);
    k_cvtx<<<dim3(64, 8, BATCH), 256, 0, stream>>>(x, xT);
    // QKV: M=1536, K=512
    k_gemm3<512, 128, false><<<dim3(32, 12, BATCH), 256, 0, stream>>>(
        xT, Wbf, qkv_all, nullptr, nullptr, nullptr, nullptr, nullptr, nullptr);
    k_dwpw  <<<dim3( 4, 192, BATCH), 256, 0, stream>>>(dwk, pwk, qkv_all);
    k_scores<<<dim3( 8, 128, BATCH),  64, 0, stream>>>(qkv_all, part);
    k_att3  <<<dim3(16, 128, BATCH), 256, 0, stream>>>(qkv_all, part, attT);
    // Proj: M=512, K=1024, + BN + residual
    k_gemm3<1024, 64, true><<<dim3(32, 8, BATCH), 256, 0, stream>>>(
        attT, Pbf, nullptr, gm, bt, mu, va, x, out);
}